// Round 1
// baseline (2218.442 us; speedup 1.0000x reference)
//
#include <hip/hip_runtime.h>

#define NVV 50000
#define NCC 50000
#define DD 128
#define FIN 32
#define INDIM 288
#define DEG 16

constexpr int L_ROWS = 32;   // rows per block
constexpr int L_BK = 32;     // k tile
constexpr int NT = 256;      // threads per block

// ---------------- init: out[r][d] = b[d] + sum_k x[r][k] * W[d][k], K=32 ----------------
__global__ __launch_bounds__(NT) void init_kernel(
    const float* __restrict__ x, const float* __restrict__ W,
    const float* __restrict__ bias, float* __restrict__ out, int nrows)
{
  __shared__ float in_t[L_ROWS][FIN + 4];
  __shared__ float W_t[DD][FIN + 4];
  const int t = threadIdx.x;
  const int row0 = blockIdx.x * L_ROWS;
  const int nvalid = min(L_ROWS, nrows - row0);

  for (int e = t; e < nvalid * FIN; e += NT)
    in_t[e >> 5][e & 31] = x[(size_t)row0 * FIN + e];
  for (int e = t; e < DD * FIN; e += NT)
    W_t[e >> 5][e & 31] = W[e];
  __syncthreads();

  const int c = t & 31, rg = t >> 5, d0 = c * 4;
  float acc[4][4];
#pragma unroll
  for (int j = 0; j < 4; ++j)
#pragma unroll
    for (int i = 0; i < 4; ++i) acc[j][i] = 0.f;

#pragma unroll
  for (int k4 = 0; k4 < FIN; k4 += 4) {
    float4 wv[4], iv[4];
#pragma unroll
    for (int i = 0; i < 4; ++i) wv[i] = *(const float4*)&W_t[d0 + i][k4];
#pragma unroll
    for (int j = 0; j < 4; ++j) iv[j] = *(const float4*)&in_t[rg * 4 + j][k4];
#pragma unroll
    for (int j = 0; j < 4; ++j)
#pragma unroll
      for (int i = 0; i < 4; ++i)
        acc[j][i] += iv[j].x * wv[i].x + iv[j].y * wv[i].y +
                     iv[j].z * wv[i].z + iv[j].w * wv[i].w;
  }
  const float4 bv = *(const float4*)&bias[d0];
#pragma unroll
  for (int j = 0; j < 4; ++j) {
    int r = rg * 4 + j;
    if (r < nvalid) {
      float4 o = make_float4(acc[j][0] + bv.x, acc[j][1] + bv.y,
                             acc[j][2] + bv.z, acc[j][3] + bv.w);
      *(float4*)&out[(size_t)(row0 + r) * DD + d0] = o;
    }
  }
}

// ------------- layer: out = [gather_sum(agg_src,idx) | self | feat] @ W^T + b -------------
__global__ __launch_bounds__(NT) void layer_kernel(
    const float* __restrict__ agg_src, const float* __restrict__ self_src,
    const float* __restrict__ feat, const int* __restrict__ idx,
    const float* __restrict__ W, const float* __restrict__ bias,
    float* __restrict__ out, int nrows)
{
  __shared__ float in_t[L_ROWS][INDIM + 4];  // 37376 B
  __shared__ float W_t[DD][L_BK + 4];        // 18432 B
  __shared__ int   idx_s[L_ROWS * DEG];      // 2048 B
  const int t = threadIdx.x;
  const int row0 = blockIdx.x * L_ROWS;
  const int nvalid = min(L_ROWS, nrows - row0);

  for (int e = t; e < nvalid * DEG; e += NT) idx_s[e] = idx[(size_t)row0 * DEG + e];
  for (int e = t; e < nvalid * FIN; e += NT)
    in_t[e >> 5][2 * DD + (e & 31)] = feat[(size_t)row0 * FIN + e];
  {
    const int d = t & 127, rh = t >> 7;
    for (int r = rh * 16; r < rh * 16 + 16; ++r)
      if (r < nvalid) in_t[r][DD + d] = self_src[(size_t)(row0 + r) * DD + d];
  }
  __syncthreads();  // idx_s visible
  {
    const int d = t & 127, rh = t >> 7;
    const int rend = min(rh * 16 + 16, nvalid);
    for (int r = rh * 16; r < rend; ++r) {
      float s = 0.f;
#pragma unroll
      for (int j = 0; j < DEG; ++j)
        s += agg_src[(size_t)idx_s[r * DEG + j] * DD + d];
      in_t[r][d] = s;
    }
  }

  const int c = t & 31, rg = t >> 5, d0 = c * 4;
  float acc[4][4];
#pragma unroll
  for (int j = 0; j < 4; ++j)
#pragma unroll
    for (int i = 0; i < 4; ++i) acc[j][i] = 0.f;

  for (int kt = 0; kt < INDIM; kt += L_BK) {
    __syncthreads();  // previous compute done (or gather done on first iter)
    for (int e = t; e < DD * L_BK; e += NT) {
      int d = e >> 5, kk = e & 31;
      W_t[d][kk] = W[(size_t)d * INDIM + kt + kk];
    }
    __syncthreads();  // W tile + input tile ready
#pragma unroll
    for (int k4 = 0; k4 < L_BK; k4 += 4) {
      float4 wv[4], iv[4];
#pragma unroll
      for (int i = 0; i < 4; ++i) wv[i] = *(const float4*)&W_t[d0 + i][k4];
#pragma unroll
      for (int j = 0; j < 4; ++j) iv[j] = *(const float4*)&in_t[rg * 4 + j][kt + k4];
#pragma unroll
      for (int j = 0; j < 4; ++j)
#pragma unroll
        for (int i = 0; i < 4; ++i)
          acc[j][i] += iv[j].x * wv[i].x + iv[j].y * wv[i].y +
                       iv[j].z * wv[i].z + iv[j].w * wv[i].w;
    }
  }

  const float4 bv = *(const float4*)&bias[d0];
#pragma unroll
  for (int j = 0; j < 4; ++j) {
    int r = rg * 4 + j;
    if (r < nvalid) {
      float4 o = make_float4(acc[j][0] + bv.x, acc[j][1] + bv.y,
                             acc[j][2] + bv.z, acc[j][3] + bv.w);
      *(float4*)&out[(size_t)(row0 + r) * DD + d0] = o;
    }
  }
}

// ---------------- g = sum_r lv[r][:] ----------------
__global__ void zero_g(float* g) { g[threadIdx.x] = 0.f; }

__global__ __launch_bounds__(NT) void reduce_kernel(
    const float* __restrict__ lv, float* __restrict__ g, int nrows)
{
  __shared__ float sh[NT];
  const int t = threadIdx.x;
  const int d = t & 127, rh = t >> 7;
  float p = 0.f;
  for (int r = blockIdx.x * 2 + rh; r < nrows; r += gridDim.x * 2)
    p += lv[(size_t)r * DD + d];
  sh[t] = p;
  __syncthreads();
  if (t < 128) atomicAdd(&g[d], sh[t] + sh[t + 128]);
}

// ------------- Q[r] = b_q + dot(Wq[0:128], g) + dot(Wq[128:256], lv[r]) -------------
__global__ __launch_bounds__(NT) void final_kernel(
    const float* __restrict__ lv, const float* __restrict__ g,
    const float* __restrict__ Wq, const float* __restrict__ bq,
    float* __restrict__ out, int nrows)
{
  __shared__ float wsum[4];
  __shared__ float qg_s;
  const int t = threadIdx.x;
  // qg = dot(Wq[0:128], g) + bq
  float q = (t < DD) ? Wq[t] * g[t] : 0.f;
#pragma unroll
  for (int off = 32; off; off >>= 1) q += __shfl_down(q, off);
  if ((t & 63) == 0) wsum[t >> 6] = q;
  __syncthreads();
  if (t == 0) qg_s = wsum[0] + wsum[1] + bq[0];
  __syncthreads();

  const int d = t & 127, rh = t >> 7;
  const int r = blockIdx.x * 2 + rh;
  float p = 0.f;
  if (r < nrows) p = Wq[DD + d] * lv[(size_t)r * DD + d];
#pragma unroll
  for (int off = 32; off; off >>= 1) p += __shfl_down(p, off);
  if ((t & 63) == 0) wsum[t >> 6] = p;
  __syncthreads();
  if (t == 0 && r < nrows) out[r] = qg_s + wsum[0] + wsum[1];
  if (t == 128 && r < nrows) out[r] = qg_s + wsum[2] + wsum[3];
}

extern "C" void kernel_launch(void* const* d_in, const int* in_sizes, int n_in,
                              void* d_out, int out_size, void* d_ws, size_t ws_size,
                              hipStream_t stream) {
  const float* x    = (const float*)d_in[0];
  const int*   vci  = (const int*)d_in[1];   // var_constr_index [NV][16]
  const int*   cvi  = (const int*)d_in[2];   // constr_var_index [NC][16]
  const float* W_iv = (const float*)d_in[3];
  const float* b_iv = (const float*)d_in[4];
  const float* W_ic = (const float*)d_in[5];
  const float* b_ic = (const float*)d_in[6];
  const float* W_v  = (const float*)d_in[7];
  const float* b_v  = (const float*)d_in[8];
  const float* W_c  = (const float*)d_in[9];
  const float* b_c  = (const float*)d_in[10];
  const float* W_q  = (const float*)d_in[11];
  const float* b_q  = (const float*)d_in[12];
  float* out = (float*)d_out;

  float* ws = (float*)d_ws;
  const size_t nodef = (size_t)NVV * DD;
  float* lv0 = ws;
  float* lc0 = lv0 + nodef;
  float* lv1 = lc0 + nodef;
  float* lc1 = lv1 + nodef;
  float* g   = lc1 + nodef;

  dim3 blk(NT);
  const int grid_n = (NVV + L_ROWS - 1) / L_ROWS;  // 1563

  init_kernel<<<grid_n, blk, 0, stream>>>(x, W_iv, b_iv, lv0, NVV);
  init_kernel<<<grid_n, blk, 0, stream>>>(x + (size_t)NVV * FIN, W_ic, b_ic, lc0, NCC);

  float* lv_cur = lv0; float* lc_cur = lc0;
  float* lv_nxt = lv1; float* lc_nxt = lc1;
  for (int l = 0; l < 3; ++l) {
    // lc_new from (old lv, old lc, con_feat)
    layer_kernel<<<grid_n, blk, 0, stream>>>(lv_cur, lc_cur, x + (size_t)NVV * FIN,
                                             cvi, W_c, b_c, lc_nxt, NCC);
    // lv_new from (old lc, old lv, var_feat)
    layer_kernel<<<grid_n, blk, 0, stream>>>(lc_cur, lv_cur, x,
                                             vci, W_v, b_v, lv_nxt, NVV);
    float* tv = lv_cur; lv_cur = lv_nxt; lv_nxt = tv;
    float* tc = lc_cur; lc_cur = lc_nxt; lc_nxt = tc;
  }

  zero_g<<<1, 128, 0, stream>>>(g);
  reduce_kernel<<<256, blk, 0, stream>>>(lv_cur, g, NVV);
  final_kernel<<<(NVV + 1) / 2, blk, 0, stream>>>(lv_cur, g, W_q, b_q, out, NVV);
}

// Round 2
// 500.648 us; speedup vs baseline: 4.4311x; 4.4311x over previous
//
#include <hip/hip_runtime.h>

#define NVV 50000
#define NCC 50000
#define DD 128
#define FIN 32
#define INDIM 288
#define DEG 16

typedef unsigned short u16;
typedef unsigned int u32;
typedef __attribute__((ext_vector_type(8))) short short8;
typedef __attribute__((ext_vector_type(4))) float f32x4;

constexpr int NT = 256;

__device__ __forceinline__ float b2f(u16 b) {
  union { u32 u; float f; } v; v.u = ((u32)b) << 16; return v.f;
}
__device__ __forceinline__ u16 f2b(float f) {
  union { float f; u32 u; } v; v.f = f;
  u32 u = v.u + 0x7FFFu + ((v.u >> 16) & 1u);
  return (u16)(u >> 16);
}

// ---------------- generic fp32 -> bf16 convert (n multiple of 4) ----------------
__global__ __launch_bounds__(NT) void convert_kernel(
    const float* __restrict__ src, u16* __restrict__ dst, int n)
{
  int i = (blockIdx.x * NT + threadIdx.x) * 4;
  if (i < n) {
    float4 v = *(const float4*)(src + i);
    u32 lo = (u32)f2b(v.x) | ((u32)f2b(v.y) << 16);
    u32 hi = (u32)f2b(v.z) | ((u32)f2b(v.w) << 16);
    u32* d = (u32*)(dst + i);
    d[0] = lo; d[1] = hi;
  }
}

// ---------------- init: out[r][d] = bf16(b[d] + sum_k x[r][k] * W[d][k]), K=32 ----------------
__global__ __launch_bounds__(NT) void init_kernel(
    const float* __restrict__ x, const float* __restrict__ W,
    const float* __restrict__ bias, u16* __restrict__ out, int nrows)
{
  __shared__ float in_t[32][FIN + 4];
  __shared__ float W_t[DD][FIN + 4];
  const int t = threadIdx.x;
  const int row0 = blockIdx.x * 32;
  const int nvalid = min(32, nrows - row0);

  for (int e = t; e < nvalid * FIN; e += NT)
    in_t[e >> 5][e & 31] = x[(size_t)row0 * FIN + e];
  for (int e = t; e < DD * FIN; e += NT)
    W_t[e >> 5][e & 31] = W[e];
  __syncthreads();

  const int c = t & 31, rg = t >> 5, d0 = c * 4;
  float acc[4][4];
#pragma unroll
  for (int j = 0; j < 4; ++j)
#pragma unroll
    for (int i = 0; i < 4; ++i) acc[j][i] = 0.f;

#pragma unroll
  for (int k4 = 0; k4 < FIN; k4 += 4) {
    float4 wv[4], iv[4];
#pragma unroll
    for (int i = 0; i < 4; ++i) wv[i] = *(const float4*)&W_t[d0 + i][k4];
#pragma unroll
    for (int j = 0; j < 4; ++j) iv[j] = *(const float4*)&in_t[rg * 4 + j][k4];
#pragma unroll
    for (int j = 0; j < 4; ++j)
#pragma unroll
      for (int i = 0; i < 4; ++i)
        acc[j][i] += iv[j].x * wv[i].x + iv[j].y * wv[i].y +
                     iv[j].z * wv[i].z + iv[j].w * wv[i].w;
  }
  const float4 bv = *(const float4*)&bias[d0];
#pragma unroll
  for (int j = 0; j < 4; ++j) {
    int r = rg * 4 + j;
    if (r < nvalid) {
      u32 lo = (u32)f2b(acc[j][0] + bv.x) | ((u32)f2b(acc[j][1] + bv.y) << 16);
      u32 hi = (u32)f2b(acc[j][2] + bv.z) | ((u32)f2b(acc[j][3] + bv.w) << 16);
      u32* d = (u32*)(out + (size_t)(row0 + r) * DD + d0);
      d[0] = lo; d[1] = hi;
    }
  }
}

// ---------------- gather: dst[r][:] = bf16( sum_j fp32(src[idx[r][j]][:]) ) ----------------
// 4 waves/block, 4 rows/wave, 16 rows/block. 50000 % 16 == 0. Zero LDS.
__global__ __launch_bounds__(NT) void gather_kernel(
    const u16* __restrict__ src, const int* __restrict__ idx,
    u16* __restrict__ dst)
{
  const int t = threadIdx.x;
  const int wave = t >> 6, l = t & 63;
  const int li = l & 15;          // 16 lanes cover one 256B row
  const int row0 = blockIdx.x * 16 + wave * 4;
  // one coalesced load grabs all 64 indices for this wave's 4 rows:
  // lane l holds idx[row0 + (l>>4)][l&15]
  const int idxv = idx[row0 * DEG + l];
  const int base = l & 48;        // (l>>4)*16

  float acc[8];
#pragma unroll
  for (int i = 0; i < 8; ++i) acc[i] = 0.f;

#pragma unroll
  for (int j = 0; j < DEG; ++j) {
    int sr = __shfl(idxv, base | j);
    short8 v = *(const short8*)(src + (size_t)sr * DD + li * 8);
#pragma unroll
    for (int i = 0; i < 8; ++i) acc[i] += b2f((u16)v[i]);
  }

  short8 o;
#pragma unroll
  for (int i = 0; i < 8; ++i) o[i] = (short)f2b(acc[i]);
  const int orow = row0 + (l >> 4);
  *(short8*)(dst + (size_t)orow * DD + li * 8) = o;
}

// ------------- layer GEMM: out = bf16([agg | self | feat] @ W^T + b) -------------
// bf16 MFMA 16x16x32, zero LDS. Block = 4 waves = 64 rows, wave = 16 rows x 128 cols.
// A frag: lane holds A[m=l&15][k=(l>>4)*8 + 0..7]  (8 contiguous K -> dwordx4)
// B frag: lane holds W[n=l&15][k=(l>>4)*8 + 0..7]
// C/D:    lane holds D[(l>>4)*4 + i][l&15]
__global__ __launch_bounds__(NT) void layer_mfma(
    const u16* __restrict__ agg, const u16* __restrict__ self,
    const u16* __restrict__ feat, const u16* __restrict__ W,
    const float* __restrict__ bias, u16* __restrict__ out, int nrows)
{
  const int t = threadIdx.x;
  const int wave = t >> 6, l = t & 63;
  const int quad = l >> 4, li = l & 15;
  const int r0 = blockIdx.x * 64 + wave * 16;
  int ra = r0 + li;
  if (ra >= nrows) ra = 0;  // clamp: garbage rows masked at store

  f32x4 acc[8];
#pragma unroll
  for (int nt = 0; nt < 8; ++nt) acc[nt] = (f32x4){0.f, 0.f, 0.f, 0.f};

#pragma unroll
  for (int kt = 0; kt < 9; ++kt) {
    short8 a;
    if (kt < 4)       a = *(const short8*)(agg  + (size_t)ra * DD  + kt * 32 + quad * 8);
    else if (kt < 8)  a = *(const short8*)(self + (size_t)ra * DD  + (kt - 4) * 32 + quad * 8);
    else              a = *(const short8*)(feat + (size_t)ra * FIN + quad * 8);
    const u16* wrow = W + (size_t)li * INDIM + kt * 32 + quad * 8;
#pragma unroll
    for (int nt = 0; nt < 8; ++nt) {
      short8 b = *(const short8*)(wrow + (size_t)nt * 16 * INDIM);
      acc[nt] = __builtin_amdgcn_mfma_f32_16x16x32_bf16(a, b, acc[nt], 0, 0, 0);
    }
  }

  const int rbase = r0 + quad * 4;
#pragma unroll
  for (int nt = 0; nt < 8; ++nt) {
    const int col = nt * 16 + li;
    const float bv = bias[col];
#pragma unroll
    for (int i = 0; i < 4; ++i) {
      const int row = rbase + i;
      if (row < nrows) out[(size_t)row * DD + col] = f2b(acc[nt][i] + bv);
    }
  }
}

// ---------------- g = sum_r lv[r][:] ----------------
__global__ void zero_g(float* g) { g[threadIdx.x] = 0.f; }

__global__ __launch_bounds__(NT) void reduce_kernel(
    const u16* __restrict__ lv, float* __restrict__ g, int nrows)
{
  __shared__ float sh[NT];
  const int t = threadIdx.x;
  const int d = t & 127, rh = t >> 7;
  float p = 0.f;
  for (int r = blockIdx.x * 2 + rh; r < nrows; r += gridDim.x * 2)
    p += b2f(lv[(size_t)r * DD + d]);
  sh[t] = p;
  __syncthreads();
  if (t < 128) atomicAdd(&g[d], sh[t] + sh[t + 128]);
}

// ------------- Q[r] = b_q + dot(Wq[0:128], g) + dot(Wq[128:256], lv[r]) -------------
__global__ __launch_bounds__(NT) void final_kernel(
    const u16* __restrict__ lv, const float* __restrict__ g,
    const float* __restrict__ Wq, const float* __restrict__ bq,
    float* __restrict__ out, int nrows)
{
  __shared__ float wsum[4];
  __shared__ float qg_s;
  const int t = threadIdx.x;
  float q = (t < DD) ? Wq[t] * g[t] : 0.f;
#pragma unroll
  for (int off = 32; off; off >>= 1) q += __shfl_down(q, off);
  if ((t & 63) == 0) wsum[t >> 6] = q;
  __syncthreads();
  if (t == 0) qg_s = wsum[0] + wsum[1] + bq[0];
  __syncthreads();

  const int d = t & 127, rh = t >> 7;
  const int r = blockIdx.x * 2 + rh;
  float p = 0.f;
  if (r < nrows) p = Wq[DD + d] * b2f(lv[(size_t)r * DD + d]);
#pragma unroll
  for (int off = 32; off; off >>= 1) p += __shfl_down(p, off);
  if ((t & 63) == 0) wsum[t >> 6] = p;
  __syncthreads();
  if (t == 0 && r < nrows) out[r] = qg_s + wsum[0] + wsum[1];
  if (t == 128 && r < nrows) out[r] = qg_s + wsum[2] + wsum[3];
}

extern "C" void kernel_launch(void* const* d_in, const int* in_sizes, int n_in,
                              void* d_out, int out_size, void* d_ws, size_t ws_size,
                              hipStream_t stream) {
  const float* x    = (const float*)d_in[0];
  const int*   vci  = (const int*)d_in[1];   // var_constr_index [NV][16] -> gathers from lc
  const int*   cvi  = (const int*)d_in[2];   // constr_var_index [NC][16] -> gathers from lv
  const float* W_iv = (const float*)d_in[3];
  const float* b_iv = (const float*)d_in[4];
  const float* W_ic = (const float*)d_in[5];
  const float* b_ic = (const float*)d_in[6];
  const float* W_v  = (const float*)d_in[7];
  const float* b_v  = (const float*)d_in[8];
  const float* W_c  = (const float*)d_in[9];
  const float* b_c  = (const float*)d_in[10];
  const float* W_q  = (const float*)d_in[11];
  const float* b_q  = (const float*)d_in[12];
  float* out = (float*)d_out;

  // workspace layout: g (fp32, 512B) then bf16 arrays (all 16B-aligned)
  float* g = (float*)d_ws;
  u16* base = (u16*)((char*)d_ws + 512);
  const size_t nodef = (size_t)NVV * DD;     // 6.4M
  u16* xb  = base;                            // 100000*32
  u16* Wvb = xb + (size_t)(NVV + NCC) * FIN;  // 128*288
  u16* Wcb = Wvb + (size_t)DD * INDIM;
  u16* lv0 = Wcb + (size_t)DD * INDIM;
  u16* lc0 = lv0 + nodef;
  u16* lv1 = lc0 + nodef;
  u16* lc1 = lv1 + nodef;
  u16* agg = lc1 + nodef;
  u16* xvb = xb;
  u16* xcb = xb + (size_t)NVV * FIN;

  dim3 blk(NT);

  convert_kernel<<<((NVV + NCC) * FIN / 4 + NT - 1) / NT, blk, 0, stream>>>(x, xb, (NVV + NCC) * FIN);
  convert_kernel<<<(DD * INDIM / 4 + NT - 1) / NT, blk, 0, stream>>>(W_v, Wvb, DD * INDIM);
  convert_kernel<<<(DD * INDIM / 4 + NT - 1) / NT, blk, 0, stream>>>(W_c, Wcb, DD * INDIM);

  const int grid_init = (NVV + 31) / 32;
  init_kernel<<<grid_init, blk, 0, stream>>>(x, W_iv, b_iv, lv0, NVV);
  init_kernel<<<grid_init, blk, 0, stream>>>(x + (size_t)NVV * FIN, W_ic, b_ic, lc0, NCC);

  const int grid_gather = NVV / 16;          // 3125 (exact)
  const int grid_layer  = (NVV + 63) / 64;   // 782

  u16* lv_cur = lv0; u16* lc_cur = lc0;
  u16* lv_nxt = lv1; u16* lc_nxt = lc1;
  for (int lyr = 0; lyr < 3; ++lyr) {
    // lc_new = [gather(lv_old, cvi) | lc_old | con_feat] @ W_c^T + b_c
    gather_kernel<<<grid_gather, blk, 0, stream>>>(lv_cur, cvi, agg);
    layer_mfma<<<grid_layer, blk, 0, stream>>>(agg, lc_cur, xcb, Wcb, b_c, lc_nxt, NCC);
    // lv_new = [gather(lc_old, vci) | lv_old | var_feat] @ W_v^T + b_v
    gather_kernel<<<grid_gather, blk, 0, stream>>>(lc_cur, vci, agg);
    layer_mfma<<<grid_layer, blk, 0, stream>>>(agg, lv_cur, xvb, Wvb, b_v, lv_nxt, NVV);
    u16* tv = lv_cur; lv_cur = lv_nxt; lv_nxt = tv;
    u16* tc = lc_cur; lc_cur = lc_nxt; lc_nxt = tc;
  }

  zero_g<<<1, 128, 0, stream>>>(g);
  reduce_kernel<<<256, blk, 0, stream>>>(lv_cur, g, NVV);
  final_kernel<<<NVV / 2, blk, 0, stream>>>(lv_cur, g, W_q, b_q, out, NVV);
}